// Round 1
// baseline (567.574 us; speedup 1.0000x reference)
//
#include <hip/hip_runtime.h>
#include <math.h>

#define DD 512
#define MM 512
#define BB 32
#define TT 4
#define VV 32000

// ---- P[p][d] = sum_t table[story[p*T+t]][d], p = b*M+m. One wave per p.
__global__ __launch_bounds__(256) void pool_kernel(const float* __restrict__ table,
                                                   const int* __restrict__ story,
                                                   float* __restrict__ P) {
  int wave = (blockIdx.x << 2) + (threadIdx.x >> 6);
  int lane = threadIdx.x & 63;
  const int* st = story + wave * TT;
  size_t r0 = (size_t)st[0] * DD, r1 = (size_t)st[1] * DD;
  size_t r2 = (size_t)st[2] * DD, r3 = (size_t)st[3] * DD;
  const float4* t4 = (const float4*)table;
  float4* p4 = (float4*)(P + (size_t)wave * DD);
#pragma unroll
  for (int h = 0; h < 2; ++h) {
    int c = (h << 6) + lane;
    float4 a = t4[(r0 >> 2) + c];
    float4 b = t4[(r1 >> 2) + c];
    float4 cc = t4[(r2 >> 2) + c];
    float4 d = t4[(r3 >> 2) + c];
    float4 r;
    r.x = a.x + b.x + cc.x + d.x;
    r.y = a.y + b.y + cc.y + d.y;
    r.z = a.z + b.z + cc.z + d.z;
    r.w = a.w + b.w + cc.w + d.w;
    p4[c] = r;
  }
}

// ---- u[b][d] (+)= sum_m w[b][m] * P[b][m][d]; w==null -> uniform 1/M (mean).
__global__ __launch_bounds__(256) void wsum_kernel(const float* __restrict__ P,
                                                   const float* __restrict__ w,
                                                   float* __restrict__ u, int init) {
  int b = blockIdx.x, d = threadIdx.x;
  const float* Pb = P + (size_t)b * MM * DD;
  float acc0 = 0.f, acc1 = 0.f;
  if (w) {
    const float* wb = w + b * MM;
#pragma unroll 8
    for (int m = 0; m < MM; ++m) {
      float wm = wb[m];
      acc0 += wm * Pb[m * DD + d];
      acc1 += wm * Pb[m * DD + d + 256];
    }
  } else {
#pragma unroll 8
    for (int m = 0; m < MM; ++m) {
      acc0 += Pb[m * DD + d];
      acc1 += Pb[m * DD + d + 256];
    }
    acc0 *= (1.0f / MM);
    acc1 *= (1.0f / MM);
  }
  int o = b * DD + d;
  if (init) { u[o] = acc0; u[o + 256] = acc1; }
  else      { u[o] += acc0; u[o + 256] += acc1; }
}

// ---- s[p] = sum_d P[p][d] * u[b][d]. One wave per p.
__global__ __launch_bounds__(256) void dot_kernel(const float* __restrict__ P,
                                                  const float* __restrict__ u,
                                                  float* __restrict__ s) {
  int p = (blockIdx.x << 2) + (threadIdx.x >> 6);
  int lane = threadIdx.x & 63;
  int b = p >> 9;  // M = 512
  const float4* Pr = (const float4*)(P + (size_t)p * DD);
  const float4* ur = (const float4*)(u + (size_t)b * DD);
  float acc = 0.f;
#pragma unroll
  for (int h = 0; h < 2; ++h) {
    int c = (h << 6) + lane;
    float4 a = Pr[c];
    float4 q = ur[c];
    acc += a.x * q.x + a.y * q.y + a.z * q.z + a.w * q.w;
  }
#pragma unroll
  for (int off = 32; off > 0; off >>= 1) acc += __shfl_xor(acc, off);
  if (lane == 0) s[p] = acc;
}

// ---- softmax over M per b. One block per b, 256 threads x 2 elems.
__global__ __launch_bounds__(256) void softmax_kernel(const float* __restrict__ s,
                                                      float* __restrict__ w) {
  __shared__ float red[16];
  int b = blockIdx.x, t = threadIdx.x;
  float v0 = s[b * MM + t], v1 = s[b * MM + t + 256];
  float mx = fmaxf(v0, v1);
#pragma unroll
  for (int off = 32; off > 0; off >>= 1) mx = fmaxf(mx, __shfl_xor(mx, off));
  if ((t & 63) == 0) red[t >> 6] = mx;
  __syncthreads();
  mx = fmaxf(fmaxf(red[0], red[1]), fmaxf(red[2], red[3]));
  float e0 = expf(v0 - mx), e1 = expf(v1 - mx);
  float sm = e0 + e1;
#pragma unroll
  for (int off = 32; off > 0; off >>= 1) sm += __shfl_xor(sm, off);
  if ((t & 63) == 0) red[8 + (t >> 6)] = sm;
  __syncthreads();
  sm = red[8] + red[9] + red[10] + red[11];
  float inv = 1.0f / sm;
  w[b * MM + t] = e0 * inv;
  w[b * MM + t + 256] = e1 * inv;
}

// ---- x[b][d] = table[q[b]][d]
__global__ void embed_kernel(const float* __restrict__ table, const int* __restrict__ q,
                             float* __restrict__ x) {
  int i = blockIdx.x * 256 + threadIdx.x;
  int b = i >> 9, d = i & 511;
  x[i] = table[(size_t)q[b] * DD + d];
}

// ---- out[b][j] = bias[j] + sum_k W[j][k] * vin[b][k]; j in [0,3D). One wave per (b,j).
__global__ __launch_bounds__(256) void matvec_kernel(const float* __restrict__ W,
                                                     const float* __restrict__ bias,
                                                     const float* __restrict__ vin,
                                                     float* __restrict__ out) {
  int idx = (blockIdx.x << 2) + (threadIdx.x >> 6);  // b*1536 + j
  int lane = threadIdx.x & 63;
  int b = idx / 1536;
  int j = idx - b * 1536;
  const float4* Wr = (const float4*)(W + (size_t)j * DD);
  const float4* xr = (const float4*)(vin + (size_t)b * DD);
  float acc = 0.f;
#pragma unroll
  for (int h = 0; h < 2; ++h) {
    int c = (h << 6) + lane;
    float4 a = Wr[c];
    float4 q = xr[c];
    acc += a.x * q.x + a.y * q.y + a.z * q.z + a.w * q.w;
  }
#pragma unroll
  for (int off = 32; off > 0; off >>= 1) acc += __shfl_xor(acc, off);
  if (lane == 0) out[idx] = acc + bias[j];
}

// ---- GRU gates: hidden = (1-z)*n + z*u
__global__ void gate_kernel(const float* __restrict__ gi, const float* __restrict__ gh,
                            const float* __restrict__ u, float* __restrict__ hidden,
                            float* __restrict__ out_h) {
  int i = blockIdx.x * 256 + threadIdx.x;  // B*D = 16384
  int b = i >> 9, d = i & 511;
  const float* gib = gi + b * 1536;
  const float* ghb = gh + b * 1536;
  float i_r = gib[d], i_z = gib[d + 512], i_n = gib[d + 1024];
  float h_r = ghb[d], h_z = ghb[d + 512], h_n = ghb[d + 1024];
  float r = 1.f / (1.f + expf(-(i_r + h_r)));
  float z = 1.f / (1.f + expf(-(i_z + h_z)));
  float n = tanhf(i_n + r * h_n);
  float h = (1.f - z) * n + z * u[i];
  hidden[i] = h;
  out_h[i] = h;
}

__global__ void vecadd_kernel(float* __restrict__ dst, const float* __restrict__ a,
                              const float* __restrict__ b) {
  int i = blockIdx.x * 256 + threadIdx.x;
  dst[i] = a[i] + b[i];
}

__global__ void hcat_kernel(float* __restrict__ hcat, const float* __restrict__ h,
                            const float* __restrict__ o) {
  int i = blockIdx.x * 256 + threadIdx.x;
  int b = i >> 9, d = i & 511;
  hcat[b * 1024 + d] = h[i];
  hcat[b * 1024 + 512 + d] = o[i];
}

// ---- p_vocab[b][v] = Hcat[b][:] . W1[v][:] + W1b[v].  C = [32 x 32000], K = 1024.
// Block tile: 32b x 256v, thread tile 4b x 8v, K-chunk 32.
__global__ __launch_bounds__(256) void pvocab_kernel(const float* __restrict__ Hcat,
                                                     const float* __restrict__ W1,
                                                     const float* __restrict__ W1b,
                                                     float* __restrict__ out) {
  __shared__ float As[32][33];
  __shared__ float Bs[32][257];
  int v0 = blockIdx.x * 256;
  int t = threadIdx.x;
  int tb = t >> 5;  // 0..7 (b-group of 4)
  int tv = t & 31;  // 0..31 (v lanes)
  float acc[4][8];
#pragma unroll
  for (int i = 0; i < 4; ++i)
#pragma unroll
    for (int j = 0; j < 8; ++j) acc[i][j] = 0.f;

  for (int k0 = 0; k0 < 1024; k0 += 32) {
    int row = t >> 3;          // 0..31
    int kk = (t & 7) << 2;     // 0,4,..,28
    float4 a = *(const float4*)(Hcat + (size_t)row * 1024 + k0 + kk);
    As[kk + 0][row] = a.x; As[kk + 1][row] = a.y;
    As[kk + 2][row] = a.z; As[kk + 3][row] = a.w;
#pragma unroll
    for (int pass = 0; pass < 8; ++pass) {
      int v = (pass << 5) + (t >> 3);
      float4 wv = *(const float4*)(W1 + (size_t)(v0 + v) * 1024 + k0 + kk);
      Bs[kk + 0][v] = wv.x; Bs[kk + 1][v] = wv.y;
      Bs[kk + 2][v] = wv.z; Bs[kk + 3][v] = wv.w;
    }
    __syncthreads();
#pragma unroll
    for (int k = 0; k < 32; ++k) {
      float av[4], bv[8];
#pragma unroll
      for (int i = 0; i < 4; ++i) av[i] = As[k][tb * 4 + i];
#pragma unroll
      for (int j = 0; j < 8; ++j) bv[j] = Bs[k][tv + 32 * j];
#pragma unroll
      for (int i = 0; i < 4; ++i)
#pragma unroll
        for (int j = 0; j < 8; ++j) acc[i][j] += av[i] * bv[j];
    }
    __syncthreads();
  }
#pragma unroll
  for (int j = 0; j < 8; ++j) {
    int v = v0 + tv + 32 * j;
    float bias = W1b[v];
#pragma unroll
    for (int i = 0; i < 4; ++i)
      out[(size_t)(tb * 4 + i) * VV + v] = acc[i][j] + bias;
  }
}

extern "C" void kernel_launch(void* const* d_in, const int* in_sizes, int n_in,
                              void* d_out, int out_size, void* d_ws, size_t ws_size,
                              hipStream_t stream) {
  const int* story = (const int*)d_in[0];
  const int* q = (const int*)d_in[1];
  const float* C_enc = (const float*)d_in[2];
  const float* C_dec = (const float*)d_in[3];
  const float* W_ih = (const float*)d_in[4];
  const float* W_hh = (const float*)d_in[5];
  const float* b_ih = (const float*)d_in[6];
  const float* b_hh = (const float*)d_in[7];
  const float* W1 = (const float*)d_in[8];
  const float* W1b = (const float*)d_in[9];
  float* out = (float*)d_out;

  const size_t VD = (size_t)VV * DD;
  float* P = (float*)d_ws;                         // [B*M*D]
  float* u = P + (size_t)BB * MM * DD;             // [B*D]
  float* s = u + BB * DD;                          // [B*M]
  float* w = s + BB * MM;                          // [B*M]
  float* x = w + BB * MM;                          // [B*D]
  float* gi = x + BB * DD;                         // [B*3D]
  float* gh = gi + BB * 3 * DD;                    // [B*3D]
  float* o = gh + BB * 3 * DD;                     // [B*D]
  float* uk = o + BB * DD;                         // [B*D]
  float* hc = uk + BB * DD;                        // [B*2D]
  float* hid = hc + BB * 2 * DD;                   // [B*D]

  float* p_ptr_out = out;
  float* p_vocab_out = out + BB * MM;
  float* hid_out = out + BB * MM + (size_t)BB * VV;

  dim3 blk(256);
  const int poolGrid = BB * MM / 4;   // 4096 (one wave per (b,m))
  const int dotGrid = BB * MM / 4;    // 4096
  const int mvGrid = BB * 3 * DD / 4; // 12288
  const int ewGrid = BB * DD / 256;   // 64

  // ---------------- Encoder (u0 = 0 => hop0 softmax is uniform; C_enc[0] unused)
  pool_kernel<<<poolGrid, blk, 0, stream>>>(C_enc + 1 * VD, story, P);
  wsum_kernel<<<BB, blk, 0, stream>>>(P, nullptr, u, 1);          // u1 = mean_m P1
  dot_kernel<<<dotGrid, blk, 0, stream>>>(P, u, s);               // s1 = P1 . u1
  softmax_kernel<<<BB, blk, 0, stream>>>(s, w);
  pool_kernel<<<poolGrid, blk, 0, stream>>>(C_enc + 2 * VD, story, P);
  wsum_kernel<<<BB, blk, 0, stream>>>(P, w, u, 0);                // u2
  dot_kernel<<<dotGrid, blk, 0, stream>>>(P, u, s);               // s2 = P2 . u2
  softmax_kernel<<<BB, blk, 0, stream>>>(s, w);
  pool_kernel<<<poolGrid, blk, 0, stream>>>(C_enc + 3 * VD, story, P);
  wsum_kernel<<<BB, blk, 0, stream>>>(P, w, u, 0);                // u3 = enc_hidden

  // ---------------- GRU step
  embed_kernel<<<ewGrid, blk, 0, stream>>>(C_dec, q, x);          // C_dec[0][enc_query]
  matvec_kernel<<<mvGrid, blk, 0, stream>>>(W_ih, b_ih, x, gi);
  matvec_kernel<<<mvGrid, blk, 0, stream>>>(W_hh, b_hh, u, gh);
  gate_kernel<<<ewGrid, blk, 0, stream>>>(gi, gh, u, hid, hid_out);

  // ---------------- Pointer decoder (C_dec[3] pooled is dead code)
  pool_kernel<<<poolGrid, blk, 0, stream>>>(C_dec + 0 * VD, story, P);
  dot_kernel<<<dotGrid, blk, 0, stream>>>(P, hid, s);             // hop0 logits
  softmax_kernel<<<BB, blk, 0, stream>>>(s, w);
  pool_kernel<<<poolGrid, blk, 0, stream>>>(C_dec + 1 * VD, story, P);
  wsum_kernel<<<BB, blk, 0, stream>>>(P, w, o, 1);                // o0
  vecadd_kernel<<<ewGrid, blk, 0, stream>>>(uk, hid, o);          // uk1
  hcat_kernel<<<ewGrid, blk, 0, stream>>>(hc, hid, o);            // [hidden, o0]
  dot_kernel<<<dotGrid, blk, 0, stream>>>(P, uk, s);              // hop1 logits (P_dec1)
  softmax_kernel<<<BB, blk, 0, stream>>>(s, w);
  pool_kernel<<<poolGrid, blk, 0, stream>>>(C_dec + 2 * VD, story, P);
  wsum_kernel<<<BB, blk, 0, stream>>>(P, w, o, 1);                // o1
  vecadd_kernel<<<ewGrid, blk, 0, stream>>>(uk, uk, o);           // uk2
  dot_kernel<<<dotGrid, blk, 0, stream>>>(P, uk, p_ptr_out);      // p_ptr = hop2 logits

  // ---------------- Vocab projection
  pvocab_kernel<<<VV / 256, blk, 0, stream>>>(hc, W1, W1b, p_vocab_out);
}

// Round 2
// 408.458 us; speedup vs baseline: 1.3896x; 1.3896x over previous
//
#include <hip/hip_runtime.h>
#include <math.h>

#define DD 512
#define MM 512
#define BB 32
#define TT 4
#define VV 32000

// ---- P[p][d] = sum_t table[story[p*T+t]][d], p = b*M+m. One wave per p.
__global__ __launch_bounds__(256) void pool_kernel(const float* __restrict__ table,
                                                   const int* __restrict__ story,
                                                   float* __restrict__ P) {
  int wave = (blockIdx.x << 2) + (threadIdx.x >> 6);
  int lane = threadIdx.x & 63;
  const int* st = story + wave * TT;
  size_t r0 = (size_t)st[0] * DD, r1 = (size_t)st[1] * DD;
  size_t r2 = (size_t)st[2] * DD, r3 = (size_t)st[3] * DD;
  const float4* t4 = (const float4*)table;
  float4* p4 = (float4*)(P + (size_t)wave * DD);
#pragma unroll
  for (int h = 0; h < 2; ++h) {
    int c = (h << 6) + lane;
    float4 a = t4[(r0 >> 2) + c];
    float4 b = t4[(r1 >> 2) + c];
    float4 cc = t4[(r2 >> 2) + c];
    float4 d = t4[(r3 >> 2) + c];
    float4 r;
    r.x = a.x + b.x + cc.x + d.x;
    r.y = a.y + b.y + cc.y + d.y;
    r.z = a.z + b.z + cc.z + d.z;
    r.w = a.w + b.w + cc.w + d.w;
    p4[c] = r;
  }
}

// ---- fused pool+dot: s[p] = (sum_t table[story[p,t]]) . u[b]  (row never stored)
__global__ __launch_bounds__(256) void pooldot_kernel(const float* __restrict__ table,
                                                      const int* __restrict__ story,
                                                      const float* __restrict__ u,
                                                      float* __restrict__ s) {
  int wave = (blockIdx.x << 2) + (threadIdx.x >> 6);
  int lane = threadIdx.x & 63;
  int b = wave >> 9;
  const int* st = story + wave * TT;
  size_t r0 = (size_t)st[0] * DD, r1 = (size_t)st[1] * DD;
  size_t r2 = (size_t)st[2] * DD, r3 = (size_t)st[3] * DD;
  const float4* t4 = (const float4*)table;
  const float4* ur = (const float4*)(u + (size_t)b * DD);
  float acc = 0.f;
#pragma unroll
  for (int h = 0; h < 2; ++h) {
    int c = (h << 6) + lane;
    float4 a = t4[(r0 >> 2) + c];
    float4 bb = t4[(r1 >> 2) + c];
    float4 cc = t4[(r2 >> 2) + c];
    float4 d = t4[(r3 >> 2) + c];
    float4 q = ur[c];
    acc += (a.x + bb.x + cc.x + d.x) * q.x;
    acc += (a.y + bb.y + cc.y + d.y) * q.y;
    acc += (a.z + bb.z + cc.z + d.z) * q.z;
    acc += (a.w + bb.w + cc.w + d.w) * q.w;
  }
#pragma unroll
  for (int off = 32; off > 0; off >>= 1) acc += __shfl_xor(acc, off);
  if (lane == 0) s[wave] = acc;
}

// ---- u[b][d] (+)= sum_m w[b][m] * P[b][m][d]; w==null -> uniform 1/M (mean).
__global__ __launch_bounds__(256) void wsum_kernel(const float* __restrict__ P,
                                                   const float* __restrict__ w,
                                                   float* __restrict__ u, int init) {
  int b = blockIdx.x, d = threadIdx.x;
  const float* Pb = P + (size_t)b * MM * DD;
  float acc0 = 0.f, acc1 = 0.f;
  if (w) {
    const float* wb = w + b * MM;
#pragma unroll 8
    for (int m = 0; m < MM; ++m) {
      float wm = wb[m];
      acc0 += wm * Pb[m * DD + d];
      acc1 += wm * Pb[m * DD + d + 256];
    }
  } else {
#pragma unroll 8
    for (int m = 0; m < MM; ++m) {
      acc0 += Pb[m * DD + d];
      acc1 += Pb[m * DD + d + 256];
    }
    acc0 *= (1.0f / MM);
    acc1 *= (1.0f / MM);
  }
  int o = b * DD + d;
  if (init) { u[o] = acc0; u[o + 256] = acc1; }
  else      { u[o] += acc0; u[o + 256] += acc1; }
}

// ---- s[p] = sum_d P[p][d] * u[b][d]. One wave per p.
__global__ __launch_bounds__(256) void dot_kernel(const float* __restrict__ P,
                                                  const float* __restrict__ u,
                                                  float* __restrict__ s) {
  int p = (blockIdx.x << 2) + (threadIdx.x >> 6);
  int lane = threadIdx.x & 63;
  int b = p >> 9;  // M = 512
  const float4* Pr = (const float4*)(P + (size_t)p * DD);
  const float4* ur = (const float4*)(u + (size_t)b * DD);
  float acc = 0.f;
#pragma unroll
  for (int h = 0; h < 2; ++h) {
    int c = (h << 6) + lane;
    float4 a = Pr[c];
    float4 q = ur[c];
    acc += a.x * q.x + a.y * q.y + a.z * q.z + a.w * q.w;
  }
#pragma unroll
  for (int off = 32; off > 0; off >>= 1) acc += __shfl_xor(acc, off);
  if (lane == 0) s[p] = acc;
}

// ---- softmax over M per b. One block per b, 256 threads x 2 elems.
__global__ __launch_bounds__(256) void softmax_kernel(const float* __restrict__ s,
                                                      float* __restrict__ w) {
  __shared__ float red[16];
  int b = blockIdx.x, t = threadIdx.x;
  float v0 = s[b * MM + t], v1 = s[b * MM + t + 256];
  float mx = fmaxf(v0, v1);
#pragma unroll
  for (int off = 32; off > 0; off >>= 1) mx = fmaxf(mx, __shfl_xor(mx, off));
  if ((t & 63) == 0) red[t >> 6] = mx;
  __syncthreads();
  mx = fmaxf(fmaxf(red[0], red[1]), fmaxf(red[2], red[3]));
  float e0 = expf(v0 - mx), e1 = expf(v1 - mx);
  float sm = e0 + e1;
#pragma unroll
  for (int off = 32; off > 0; off >>= 1) sm += __shfl_xor(sm, off);
  if ((t & 63) == 0) red[8 + (t >> 6)] = sm;
  __syncthreads();
  sm = red[8] + red[9] + red[10] + red[11];
  float inv = 1.0f / sm;
  w[b * MM + t] = e0 * inv;
  w[b * MM + t + 256] = e1 * inv;
}

// ---- x[b][d] = table[q[b]][d]
__global__ void embed_kernel(const float* __restrict__ table, const int* __restrict__ q,
                             float* __restrict__ x) {
  int i = blockIdx.x * 256 + threadIdx.x;
  int b = i >> 9, d = i & 511;
  x[i] = table[(size_t)q[b] * DD + d];
}

// ---- out[b][j] = bias[j] + sum_k W[j][k] * vin[b][k]; j in [0,3D). One wave per (b,j).
__global__ __launch_bounds__(256) void matvec_kernel(const float* __restrict__ W,
                                                     const float* __restrict__ bias,
                                                     const float* __restrict__ vin,
                                                     float* __restrict__ out) {
  int idx = (blockIdx.x << 2) + (threadIdx.x >> 6);  // b*1536 + j
  int lane = threadIdx.x & 63;
  int b = idx / 1536;
  int j = idx - b * 1536;
  const float4* Wr = (const float4*)(W + (size_t)j * DD);
  const float4* xr = (const float4*)(vin + (size_t)b * DD);
  float acc = 0.f;
#pragma unroll
  for (int h = 0; h < 2; ++h) {
    int c = (h << 6) + lane;
    float4 a = Wr[c];
    float4 q = xr[c];
    acc += a.x * q.x + a.y * q.y + a.z * q.z + a.w * q.w;
  }
#pragma unroll
  for (int off = 32; off > 0; off >>= 1) acc += __shfl_xor(acc, off);
  if (lane == 0) out[idx] = acc + bias[j];
}

// ---- GRU gates: hidden = (1-z)*n + z*u
__global__ void gate_kernel(const float* __restrict__ gi, const float* __restrict__ gh,
                            const float* __restrict__ u, float* __restrict__ hidden,
                            float* __restrict__ out_h) {
  int i = blockIdx.x * 256 + threadIdx.x;  // B*D = 16384
  int b = i >> 9, d = i & 511;
  const float* gib = gi + b * 1536;
  const float* ghb = gh + b * 1536;
  float i_r = gib[d], i_z = gib[d + 512], i_n = gib[d + 1024];
  float h_r = ghb[d], h_z = ghb[d + 512], h_n = ghb[d + 1024];
  float r = 1.f / (1.f + expf(-(i_r + h_r)));
  float z = 1.f / (1.f + expf(-(i_z + h_z)));
  float n = tanhf(i_n + r * h_n);
  float h = (1.f - z) * n + z * u[i];
  hidden[i] = h;
  out_h[i] = h;
}

__global__ void vecadd_kernel(float* __restrict__ dst, const float* __restrict__ a,
                              const float* __restrict__ b) {
  int i = blockIdx.x * 256 + threadIdx.x;
  dst[i] = a[i] + b[i];
}

// ---- hcat = [h | o], uk = h + o   (fused)
__global__ void hcatadd_kernel(float* __restrict__ hcat, float* __restrict__ uk,
                               const float* __restrict__ h, const float* __restrict__ o) {
  int i = blockIdx.x * 256 + threadIdx.x;
  int b = i >> 9, d = i & 511;
  float hv = h[i], ov = o[i];
  hcat[b * 1024 + d] = hv;
  hcat[b * 1024 + 512 + d] = ov;
  uk[i] = hv + ov;
}

// ---- p_vocab[b][v] = Hcat[b][:] . W1[v][:] + W1b[v].  [32 x 32000], K = 1024.
// 512 threads, block tile 32b x 128v, thread tile 4b x 2v, K-chunk 32,
// register double-buffer for global->LDS staging. Grid = 250.
__global__ __launch_bounds__(512) void pvocab_kernel(const float* __restrict__ Hcat,
                                                     const float* __restrict__ W1,
                                                     const float* __restrict__ W1b,
                                                     float* __restrict__ out) {
  __shared__ float As[32][36];    // [k][b] (+pad, rows 144B: 16B-aligned)
  __shared__ float Bs[32][132];   // [k][v] (+pad, rows 528B: 16B-aligned)
  int t = threadIdx.x;
  int v0 = blockIdx.x * 128;
  int tb = t >> 6;          // 0..7 : b-group (wave-uniform)
  int tv = t & 63;          // 0..63: v-pair lane
  // B staging: r = t>>2 (0..127 vocab rows), bk = (t&3)*8 (k-offset)
  int br = t >> 2;
  int bk = (t & 3) << 3;
  const float* Wp = W1 + (size_t)(v0 + br) * 1024 + bk;
  // A staging (threads 0..255): ab = t>>3 (0..31), ak = (t&7)*4
  int ab = t >> 3;
  int ak = (t & 7) << 2;
  const float* Ap = Hcat + (size_t)ab * 1024 + ak;

  float acc[4][2] = {{0.f, 0.f}, {0.f, 0.f}, {0.f, 0.f}, {0.f, 0.f}};

  float4 aReg = make_float4(0.f, 0.f, 0.f, 0.f);
  float4 wReg0, wReg1;
  if (t < 256) aReg = *(const float4*)(Ap);
  wReg0 = *(const float4*)(Wp);
  wReg1 = *(const float4*)(Wp + 4);

  for (int k0 = 0; k0 < 1024; k0 += 32) {
    if (t < 256) {
      As[ak + 0][ab] = aReg.x; As[ak + 1][ab] = aReg.y;
      As[ak + 2][ab] = aReg.z; As[ak + 3][ab] = aReg.w;
    }
    Bs[bk + 0][br] = wReg0.x; Bs[bk + 1][br] = wReg0.y;
    Bs[bk + 2][br] = wReg0.z; Bs[bk + 3][br] = wReg0.w;
    Bs[bk + 4][br] = wReg1.x; Bs[bk + 5][br] = wReg1.y;
    Bs[bk + 6][br] = wReg1.z; Bs[bk + 7][br] = wReg1.w;
    __syncthreads();
    if (k0 + 32 < 1024) {   // issue next chunk's loads early; latency hides under FMAs
      if (t < 256) aReg = *(const float4*)(Ap + k0 + 32);
      wReg0 = *(const float4*)(Wp + k0 + 32);
      wReg1 = *(const float4*)(Wp + k0 + 36);
    }
#pragma unroll
    for (int k = 0; k < 32; ++k) {
      float2 bv = *(const float2*)&Bs[k][tv * 2];
      float4 av = *(const float4*)&As[k][tb * 4];   // wave-uniform broadcast
      acc[0][0] += av.x * bv.x; acc[0][1] += av.x * bv.y;
      acc[1][0] += av.y * bv.x; acc[1][1] += av.y * bv.y;
      acc[2][0] += av.z * bv.x; acc[2][1] += av.z * bv.y;
      acc[3][0] += av.w * bv.x; acc[3][1] += av.w * bv.y;
    }
    __syncthreads();
  }
  int v = v0 + tv * 2;
  float b0 = W1b[v], b1 = W1b[v + 1];
#pragma unroll
  for (int i = 0; i < 4; ++i) {
    float2 r;
    r.x = acc[i][0] + b0;
    r.y = acc[i][1] + b1;
    *(float2*)(out + (size_t)(tb * 4 + i) * VV + v) = r;
  }
}

extern "C" void kernel_launch(void* const* d_in, const int* in_sizes, int n_in,
                              void* d_out, int out_size, void* d_ws, size_t ws_size,
                              hipStream_t stream) {
  const int* story = (const int*)d_in[0];
  const int* q = (const int*)d_in[1];
  const float* C_enc = (const float*)d_in[2];
  const float* C_dec = (const float*)d_in[3];
  const float* W_ih = (const float*)d_in[4];
  const float* W_hh = (const float*)d_in[5];
  const float* b_ih = (const float*)d_in[6];
  const float* b_hh = (const float*)d_in[7];
  const float* W1 = (const float*)d_in[8];
  const float* W1b = (const float*)d_in[9];
  float* out = (float*)d_out;

  const size_t VD = (size_t)VV * DD;
  float* P = (float*)d_ws;                         // [B*M*D]
  float* u = P + (size_t)BB * MM * DD;             // [B*D]
  float* s = u + BB * DD;                          // [B*M]
  float* w = s + BB * MM;                          // [B*M]
  float* x = w + BB * MM;                          // [B*D]
  float* gi = x + BB * DD;                         // [B*3D]
  float* gh = gi + BB * 3 * DD;                    // [B*3D]
  float* o = gh + BB * 3 * DD;                     // [B*D]
  float* uk = o + BB * DD;                         // [B*D]
  float* hc = uk + BB * DD;                        // [B*2D]
  float* hid = hc + BB * 2 * DD;                   // [B*D]

  float* p_ptr_out = out;
  float* p_vocab_out = out + BB * MM;
  float* hid_out = out + BB * MM + (size_t)BB * VV;

  dim3 blk(256);
  const int poolGrid = BB * MM / 4;   // 4096 (one wave per (b,m))
  const int dotGrid = BB * MM / 4;    // 4096
  const int mvGrid = BB * 3 * DD / 4; // 12288
  const int ewGrid = BB * DD / 256;   // 64

  // ---------------- Encoder (u0 = 0 => hop0 softmax is uniform; C_enc[0] unused)
  pool_kernel<<<poolGrid, blk, 0, stream>>>(C_enc + 1 * VD, story, P);
  wsum_kernel<<<BB, blk, 0, stream>>>(P, nullptr, u, 1);          // u1 = mean_m P1
  dot_kernel<<<dotGrid, blk, 0, stream>>>(P, u, s);               // s1 = P1 . u1
  softmax_kernel<<<BB, blk, 0, stream>>>(s, w);
  pool_kernel<<<poolGrid, blk, 0, stream>>>(C_enc + 2 * VD, story, P);
  wsum_kernel<<<BB, blk, 0, stream>>>(P, w, u, 0);                // u2
  dot_kernel<<<dotGrid, blk, 0, stream>>>(P, u, s);               // s2 = P2 . u2
  softmax_kernel<<<BB, blk, 0, stream>>>(s, w);
  pool_kernel<<<poolGrid, blk, 0, stream>>>(C_enc + 3 * VD, story, P);
  wsum_kernel<<<BB, blk, 0, stream>>>(P, w, u, 0);                // u3 = enc_hidden

  // ---------------- GRU step
  embed_kernel<<<ewGrid, blk, 0, stream>>>(C_dec, q, x);          // C_dec[0][enc_query]
  matvec_kernel<<<mvGrid, blk, 0, stream>>>(W_ih, b_ih, x, gi);
  matvec_kernel<<<mvGrid, blk, 0, stream>>>(W_hh, b_hh, u, gh);
  gate_kernel<<<ewGrid, blk, 0, stream>>>(gi, gh, u, hid, hid_out);

  // ---------------- Pointer decoder (C_dec[3] pooled is dead code)
  pooldot_kernel<<<poolGrid, blk, 0, stream>>>(C_dec + 0 * VD, story, hid, s); // hop0 logits (fused)
  softmax_kernel<<<BB, blk, 0, stream>>>(s, w);
  pool_kernel<<<poolGrid, blk, 0, stream>>>(C_dec + 1 * VD, story, P);
  wsum_kernel<<<BB, blk, 0, stream>>>(P, w, o, 1);                // o0
  hcatadd_kernel<<<ewGrid, blk, 0, stream>>>(hc, uk, hid, o);     // hcat=[hid|o0], uk1=hid+o0
  dot_kernel<<<dotGrid, blk, 0, stream>>>(P, uk, s);              // hop1 logits
  softmax_kernel<<<BB, blk, 0, stream>>>(s, w);
  pool_kernel<<<poolGrid, blk, 0, stream>>>(C_dec + 2 * VD, story, P);
  wsum_kernel<<<BB, blk, 0, stream>>>(P, w, o, 1);                // o1
  vecadd_kernel<<<ewGrid, blk, 0, stream>>>(uk, uk, o);           // uk2
  dot_kernel<<<dotGrid, blk, 0, stream>>>(P, uk, p_ptr_out);      // p_ptr = hop2 logits

  // ---------------- Vocab projection
  pvocab_kernel<<<VV / 128, dim3(512), 0, stream>>>(hc, W1, W1b, p_vocab_out);
}

// Round 3
// 314.230 us; speedup vs baseline: 1.8062x; 1.2999x over previous
//
#include <hip/hip_runtime.h>
#include <math.h>

#define DD 512
#define MM 512
#define BB 32
#define TT 4
#define VV 32000
#define BMD ((size_t)BB * MM * DD)   // 8388608

// ---- all 6 pooled tables in one launch. grid = 6*4096 blocks, 4 waves/block,
// one (table, b, m) per wave. P_k[p][d] = sum_t table_k[story[p*T+t]][d].
__global__ __launch_bounds__(256) void mega_pool(const float* __restrict__ C_enc,
                                                 const float* __restrict__ C_dec,
                                                 const int* __restrict__ story,
                                                 float* __restrict__ P) {
  int g = blockIdx.x;
  int tbl = g >> 12;                 // 0..5
  int blk = g & 4095;
  int wave = (blk << 2) + (threadIdx.x >> 6);
  int lane = threadIdx.x & 63;
  const size_t VD = (size_t)VV * DD;
  const float* table = (tbl < 3) ? (C_enc + (size_t)(tbl + 1) * VD)
                                 : (C_dec + (size_t)(tbl - 3) * VD);
  const int* st = story + wave * TT;
  size_t r0 = (size_t)st[0] * DD, r1 = (size_t)st[1] * DD;
  size_t r2 = (size_t)st[2] * DD, r3 = (size_t)st[3] * DD;
  const float4* t4 = (const float4*)table;
  float4* p4 = (float4*)(P + (size_t)tbl * BMD + (size_t)wave * DD);
#pragma unroll
  for (int h = 0; h < 2; ++h) {
    int c = (h << 6) + lane;
    float4 a = t4[(r0 >> 2) + c];
    float4 b = t4[(r1 >> 2) + c];
    float4 cc = t4[(r2 >> 2) + c];
    float4 d = t4[(r3 >> 2) + c];
    float4 r;
    r.x = a.x + b.x + cc.x + d.x;
    r.y = a.y + b.y + cc.y + d.y;
    r.z = a.z + b.z + cc.z + d.z;
    r.w = a.w + b.w + cc.w + d.w;
    p4[c] = r;
  }
}

// ---- stage A of weighted sum: partial[(b*8+c)][d] = sum_{m in chunk c} w[b][m]*P[b][m][d]
// w = softmax(s[b]) computed redundantly in-block (8x, trivial); s==null -> 1/M.
__global__ __launch_bounds__(256) void wsumA_kernel(const float* __restrict__ P,
                                                    const float* __restrict__ s,
                                                    float* __restrict__ partial) {
  __shared__ float wsh[MM];
  __shared__ float red[16];
  int b = blockIdx.x >> 3;
  int c = blockIdx.x & 7;
  int t = threadIdx.x;
  if (s) {
    float v0 = s[b * MM + t], v1 = s[b * MM + t + 256];
    float mx = fmaxf(v0, v1);
#pragma unroll
    for (int off = 32; off > 0; off >>= 1) mx = fmaxf(mx, __shfl_xor(mx, off));
    if ((t & 63) == 0) red[t >> 6] = mx;
    __syncthreads();
    mx = fmaxf(fmaxf(red[0], red[1]), fmaxf(red[2], red[3]));
    float e0 = expf(v0 - mx), e1 = expf(v1 - mx);
    float sm = e0 + e1;
#pragma unroll
    for (int off = 32; off > 0; off >>= 1) sm += __shfl_xor(sm, off);
    if ((t & 63) == 0) red[8 + (t >> 6)] = sm;
    __syncthreads();
    sm = red[8] + red[9] + red[10] + red[11];
    float inv = 1.0f / sm;
    wsh[t] = e0 * inv;
    wsh[t + 256] = e1 * inv;
    __syncthreads();
  }
  const float* Pb = P + ((size_t)b * MM + c * 64) * DD;
  float acc0 = 0.f, acc1 = 0.f;
  if (s) {
#pragma unroll 8
    for (int m = 0; m < 64; ++m) {
      float wm = wsh[c * 64 + m];
      acc0 += wm * Pb[m * DD + t];
      acc1 += wm * Pb[m * DD + t + 256];
    }
  } else {
#pragma unroll 8
    for (int m = 0; m < 64; ++m) {
      acc0 += Pb[m * DD + t];
      acc1 += Pb[m * DD + t + 256];
    }
    acc0 *= (1.0f / MM);
    acc1 *= (1.0f / MM);
  }
  float* pp = partial + (size_t)blockIdx.x * DD;
  pp[t] = acc0;
  pp[t + 256] = acc1;
}

// ---- stage B: uout[b][d] = (prev ? prev[b][d] : 0) + sum_{c<8} partial[b*8+c][d]
__global__ void wsumB_kernel(const float* __restrict__ partial,
                             const float* __restrict__ prev,
                             float* __restrict__ uout) {
  int i = blockIdx.x * 256 + threadIdx.x;   // 64 blocks -> B*D
  int b = i >> 9, d = i & 511;
  float acc = prev ? prev[i] : 0.f;
  const float* pp = partial + (size_t)b * 8 * DD + d;
#pragma unroll
  for (int c = 0; c < 8; ++c) acc += pp[c * DD];
  uout[i] = acc;
}

// ---- stage B, decoder hop0: o0 = sum partials; uk = hid + o0; hc = [hid | o0]
__global__ void wsumB2_kernel(const float* __restrict__ partial,
                              const float* __restrict__ hid,
                              float* __restrict__ uk, float* __restrict__ hc) {
  int i = blockIdx.x * 256 + threadIdx.x;
  int b = i >> 9, d = i & 511;
  float ov = 0.f;
  const float* pp = partial + (size_t)b * 8 * DD + d;
#pragma unroll
  for (int c = 0; c < 8; ++c) ov += pp[c * DD];
  float hv = hid[i];
  uk[i] = hv + ov;
  hc[b * 1024 + d] = hv;
  hc[b * 1024 + 512 + d] = ov;
}

// ---- s[p] = sum_d P[p][d] * u[b][d]. One wave per p.
__global__ __launch_bounds__(256) void dot_kernel(const float* __restrict__ P,
                                                  const float* __restrict__ u,
                                                  float* __restrict__ s) {
  int p = (blockIdx.x << 2) + (threadIdx.x >> 6);
  int lane = threadIdx.x & 63;
  int b = p >> 9;
  const float4* Pr = (const float4*)(P + (size_t)p * DD);
  const float4* ur = (const float4*)(u + (size_t)b * DD);
  float acc = 0.f;
#pragma unroll
  for (int h = 0; h < 2; ++h) {
    int c = (h << 6) + lane;
    float4 a = Pr[c];
    float4 q = ur[c];
    acc += a.x * q.x + a.y * q.y + a.z * q.z + a.w * q.w;
  }
#pragma unroll
  for (int off = 32; off > 0; off >>= 1) acc += __shfl_xor(acc, off);
  if (lane == 0) s[p] = acc;
}

// ---- out[b][j] = bias[j] + W[j]. (vin ? vin[b] : table[q[b]]). One wave per (b,j).
__global__ __launch_bounds__(256) void matvec_kernel(const float* __restrict__ W,
                                                     const float* __restrict__ bias,
                                                     const float* __restrict__ vin,
                                                     const int* __restrict__ q,
                                                     const float* __restrict__ table,
                                                     float* __restrict__ out) {
  int idx = (blockIdx.x << 2) + (threadIdx.x >> 6);  // b*1536 + j
  int lane = threadIdx.x & 63;
  int b = idx / 1536;
  int j = idx - b * 1536;
  const float* xb = vin ? (vin + (size_t)b * DD) : (table + (size_t)q[b] * DD);
  const float4* Wr = (const float4*)(W + (size_t)j * DD);
  const float4* xr = (const float4*)xb;
  float acc = 0.f;
#pragma unroll
  for (int h = 0; h < 2; ++h) {
    int c = (h << 6) + lane;
    float4 a = Wr[c];
    float4 qv = xr[c];
    acc += a.x * qv.x + a.y * qv.y + a.z * qv.z + a.w * qv.w;
  }
#pragma unroll
  for (int off = 32; off > 0; off >>= 1) acc += __shfl_xor(acc, off);
  if (lane == 0) out[idx] = acc + bias[j];
}

// ---- GRU gates: hidden = (1-z)*n + z*u
__global__ void gate_kernel(const float* __restrict__ gi, const float* __restrict__ gh,
                            const float* __restrict__ u, float* __restrict__ hidden,
                            float* __restrict__ out_h) {
  int i = blockIdx.x * 256 + threadIdx.x;  // B*D
  int b = i >> 9, d = i & 511;
  const float* gib = gi + b * 1536;
  const float* ghb = gh + b * 1536;
  float i_r = gib[d], i_z = gib[d + 512], i_n = gib[d + 1024];
  float h_r = ghb[d], h_z = ghb[d + 512], h_n = ghb[d + 1024];
  float r = 1.f / (1.f + expf(-(i_r + h_r)));
  float z = 1.f / (1.f + expf(-(i_z + h_z)));
  float n = tanhf(i_n + r * h_n);
  float h = (1.f - z) * n + z * u[i];
  hidden[i] = h;
  out_h[i] = h;
}

// ---- p_vocab[b][v] = Hcat[b][:] . W1[v][:] + W1b[v].  [32 x 32000], K = 1024.
// 256 threads, block tile 32b x 64v, thread tile 4b x 2v, K-chunk 32,
// register double-buffer staging. Grid = 500 (2 blocks/CU).
__global__ __launch_bounds__(256) void pvocab_kernel(const float* __restrict__ Hcat,
                                                     const float* __restrict__ W1,
                                                     const float* __restrict__ W1b,
                                                     float* __restrict__ out) {
  __shared__ float As[32][36];   // [k][b] + pad
  __shared__ float Bs[32][68];   // [k][v] + pad
  int t = threadIdx.x;
  int v0 = blockIdx.x * 64;
  int tb = t >> 5;          // 0..7 : b-group of 4 (uniform per 32-lane half)
  int tv = t & 31;          // 0..31: v-pair
  // B staging: row = t>>2 (0..63 vocab rows), bk = (t&3)*8
  int br = t >> 2;
  int bk = (t & 3) << 3;
  const float* Wp = W1 + (size_t)(v0 + br) * 1024 + bk;
  // A staging: ab = t>>3 (0..31), ak = (t&7)*4
  int ab = t >> 3;
  int ak = (t & 7) << 2;
  const float* Ap = Hcat + (size_t)ab * 1024 + ak;

  float acc[4][2] = {{0.f, 0.f}, {0.f, 0.f}, {0.f, 0.f}, {0.f, 0.f}};

  float4 aReg = *(const float4*)(Ap);
  float4 wReg0 = *(const float4*)(Wp);
  float4 wReg1 = *(const float4*)(Wp + 4);

  for (int k0 = 0; k0 < 1024; k0 += 32) {
    As[ak + 0][ab] = aReg.x; As[ak + 1][ab] = aReg.y;
    As[ak + 2][ab] = aReg.z; As[ak + 3][ab] = aReg.w;
    Bs[bk + 0][br] = wReg0.x; Bs[bk + 1][br] = wReg0.y;
    Bs[bk + 2][br] = wReg0.z; Bs[bk + 3][br] = wReg0.w;
    Bs[bk + 4][br] = wReg1.x; Bs[bk + 5][br] = wReg1.y;
    Bs[bk + 6][br] = wReg1.z; Bs[bk + 7][br] = wReg1.w;
    __syncthreads();
    if (k0 + 32 < 1024) {   // issue next chunk early; hides under FMAs
      aReg = *(const float4*)(Ap + k0 + 32);
      wReg0 = *(const float4*)(Wp + k0 + 32);
      wReg1 = *(const float4*)(Wp + k0 + 36);
    }
#pragma unroll
    for (int k = 0; k < 32; ++k) {
      float2 bv = *(const float2*)&Bs[k][tv * 2];
      float4 av = *(const float4*)&As[k][tb * 4];
      acc[0][0] += av.x * bv.x; acc[0][1] += av.x * bv.y;
      acc[1][0] += av.y * bv.x; acc[1][1] += av.y * bv.y;
      acc[2][0] += av.z * bv.x; acc[2][1] += av.z * bv.y;
      acc[3][0] += av.w * bv.x; acc[3][1] += av.w * bv.y;
    }
    __syncthreads();
  }
  int v = v0 + tv * 2;
  float b0 = W1b[v], b1 = W1b[v + 1];
#pragma unroll
  for (int i = 0; i < 4; ++i) {
    float2 r;
    r.x = acc[i][0] + b0;
    r.y = acc[i][1] + b1;
    *(float2*)(out + (size_t)(tb * 4 + i) * VV + v) = r;
  }
}

extern "C" void kernel_launch(void* const* d_in, const int* in_sizes, int n_in,
                              void* d_out, int out_size, void* d_ws, size_t ws_size,
                              hipStream_t stream) {
  const int* story = (const int*)d_in[0];
  const int* q = (const int*)d_in[1];
  const float* C_enc = (const float*)d_in[2];
  const float* C_dec = (const float*)d_in[3];
  const float* W_ih = (const float*)d_in[4];
  const float* W_hh = (const float*)d_in[5];
  const float* b_ih = (const float*)d_in[6];
  const float* b_hh = (const float*)d_in[7];
  const float* W1 = (const float*)d_in[8];
  const float* W1b = (const float*)d_in[9];
  float* out = (float*)d_out;

  float* P = (float*)d_ws;                 // 6 x [B*M*D]
  float* u = P + 6 * BMD;                  // [B*D]
  float* s = u + BB * DD;                  // [B*M]
  float* part = s + BB * MM;               // [B*8*D]
  float* gi = part + BB * 8 * DD;          // [B*3D]
  float* gh = gi + BB * 3 * DD;            // [B*3D]
  float* hid = gh + BB * 3 * DD;           // [B*D]
  float* uk = hid + BB * DD;               // [B*D]
  float* hc = uk + BB * DD;                // [B*2D]

  const float* P0 = P;                     // C_enc[1] pooled
  const float* P1 = P + 1 * BMD;           // C_enc[2]
  const float* P2 = P + 2 * BMD;           // C_enc[3]
  const float* P3 = P + 3 * BMD;           // C_dec[0]
  const float* P4 = P + 4 * BMD;           // C_dec[1]
  const float* P5 = P + 5 * BMD;           // C_dec[2]

  float* p_ptr_out = out;
  float* p_vocab_out = out + BB * MM;
  float* hid_out = out + BB * MM + (size_t)BB * VV;

  dim3 blk(256);
  const int dotGrid = BB * MM / 4;    // 1024 blocks x 4 waves
  const int mvGrid = BB * 3 * DD / 4; // 3072 blocks
  const int ewGrid = BB * DD / 256;   // 64

  // ---------------- all gathers upfront (mutually independent)
  mega_pool<<<6 * 4096, blk, 0, stream>>>(C_enc, C_dec, story, P);

  // ---------------- encoder (u0 = 0 => hop0 softmax uniform; C_enc[0] unused)
  wsumA_kernel<<<BB * 8, blk, 0, stream>>>(P0, nullptr, part);
  wsumB_kernel<<<ewGrid, blk, 0, stream>>>(part, nullptr, u);     // u1
  dot_kernel<<<dotGrid, blk, 0, stream>>>(P0, u, s);              // s1
  wsumA_kernel<<<BB * 8, blk, 0, stream>>>(P1, s, part);          // softmax folded
  wsumB_kernel<<<ewGrid, blk, 0, stream>>>(part, u, u);           // u2
  dot_kernel<<<dotGrid, blk, 0, stream>>>(P1, u, s);              // s2
  wsumA_kernel<<<BB * 8, blk, 0, stream>>>(P2, s, part);
  wsumB_kernel<<<ewGrid, blk, 0, stream>>>(part, u, u);           // u3 = enc_hidden

  // ---------------- GRU step (embed folded into matvec_gi)
  matvec_kernel<<<mvGrid, blk, 0, stream>>>(W_ih, b_ih, nullptr, q, C_dec, gi);
  matvec_kernel<<<mvGrid, blk, 0, stream>>>(W_hh, b_hh, u, nullptr, nullptr, gh);
  gate_kernel<<<ewGrid, blk, 0, stream>>>(gi, gh, u, hid, hid_out);

  // ---------------- pointer decoder (C_dec[3] pooled is dead code)
  dot_kernel<<<dotGrid, blk, 0, stream>>>(P3, hid, s);            // hop0 logits
  wsumA_kernel<<<BB * 8, blk, 0, stream>>>(P4, s, part);
  wsumB2_kernel<<<ewGrid, blk, 0, stream>>>(part, hid, uk, hc);   // o0, uk1, hcat
  dot_kernel<<<dotGrid, blk, 0, stream>>>(P4, uk, s);             // hop1 logits
  wsumA_kernel<<<BB * 8, blk, 0, stream>>>(P5, s, part);
  wsumB_kernel<<<ewGrid, blk, 0, stream>>>(part, uk, uk);         // uk2
  dot_kernel<<<dotGrid, blk, 0, stream>>>(P5, uk, p_ptr_out);     // p_ptr

  // ---------------- vocab projection
  pvocab_kernel<<<VV / 64, blk, 0, stream>>>(hc, W1, W1b, p_vocab_out);
}

// Round 4
// 297.703 us; speedup vs baseline: 1.9065x; 1.0555x over previous
//
#include <hip/hip_runtime.h>
#include <math.h>

#define DD 512
#define MM 512
#define BB 32
#define TT 4
#define VV 32000

// ---- fused gather + (softmax-weighted) partial sum.
// block = b*32 + c; handles m in [c*16, c*16+16) -> 64 story rows.
// partial[(b*32+c)][d] = sum_{m in chunk} w[b][m] * sum_t table[story[b,m,t]][d]
// w = softmax(s[b]) computed redundantly per block; s==null -> 1/M (mean pool).
__global__ __launch_bounds__(256) void poolwsum_kernel(const float* __restrict__ table,
                                                       const int* __restrict__ story,
                                                       const float* __restrict__ s,
                                                       float* __restrict__ partial) {
  __shared__ float wsh[16];
  __shared__ int rows[64];
  __shared__ float red[16];
  int b = blockIdx.x >> 5;
  int c = blockIdx.x & 31;
  int t = threadIdx.x;
  if (s) {
    float v0 = s[b * MM + t], v1 = s[b * MM + t + 256];
    float mx = fmaxf(v0, v1);
#pragma unroll
    for (int off = 32; off > 0; off >>= 1) mx = fmaxf(mx, __shfl_xor(mx, off));
    if ((t & 63) == 0) red[t >> 6] = mx;
    __syncthreads();
    mx = fmaxf(fmaxf(red[0], red[1]), fmaxf(red[2], red[3]));
    float e0 = expf(v0 - mx), e1 = expf(v1 - mx);
    float sm = e0 + e1;
#pragma unroll
    for (int off = 32; off > 0; off >>= 1) sm += __shfl_xor(sm, off);
    if ((t & 63) == 0) red[8 + (t >> 6)] = sm;
    __syncthreads();
    sm = red[8] + red[9] + red[10] + red[11];
    float inv = 1.0f / sm;
    if (t < 16) wsh[t] = expf(s[b * MM + c * 16 + t] - mx) * inv;
  } else {
    if (t < 16) wsh[t] = 1.0f / MM;
  }
  if (t < 64) rows[t] = story[((b << 9) + (c << 4)) * TT + t];
  __syncthreads();
  float acc0 = 0.f, acc1 = 0.f;
#pragma unroll 8
  for (int i = 0; i < 64; ++i) {
    const float* r = table + (size_t)rows[i] * DD;
    float wm = wsh[i >> 2];
    acc0 += wm * r[t];
    acc1 += wm * r[t + 256];
  }
  float* pp = partial + (size_t)blockIdx.x * DD;
  pp[t] = acc0;
  pp[t + 256] = acc1;
}

// ---- stage B: uout[b][d] = (prev ? prev[b][d] : 0) + sum_{c<32} partial[b*32+c][d]
__global__ void wsumB_kernel(const float* __restrict__ partial,
                             const float* __restrict__ prev,
                             float* __restrict__ uout) {
  int i = blockIdx.x * 256 + threadIdx.x;   // 64 blocks -> B*D
  int b = i >> 9, d = i & 511;
  float acc = prev ? prev[i] : 0.f;
  const float* pp = partial + (size_t)b * 32 * DD + d;
#pragma unroll
  for (int c = 0; c < 32; ++c) acc += pp[c * DD];
  uout[i] = acc;
}

// ---- stage B, decoder hop0: o0 = sum partials; uk = hid + o0; hc = [hid | o0]
__global__ void wsumB2_kernel(const float* __restrict__ partial,
                              const float* __restrict__ hid,
                              float* __restrict__ uk, float* __restrict__ hc) {
  int i = blockIdx.x * 256 + threadIdx.x;
  int b = i >> 9, d = i & 511;
  float ov = 0.f;
  const float* pp = partial + (size_t)b * 32 * DD + d;
#pragma unroll
  for (int c = 0; c < 32; ++c) ov += pp[c * DD];
  float hv = hid[i];
  uk[i] = hv + ov;
  hc[b * 1024 + d] = hv;
  hc[b * 1024 + 512 + d] = ov;
}

// ---- fused gather + dot: s[p] = (sum_t table[story[p,t]]) . u[b]. One wave per p.
__global__ __launch_bounds__(256) void pooldot_kernel(const float* __restrict__ table,
                                                      const int* __restrict__ story,
                                                      const float* __restrict__ u,
                                                      float* __restrict__ s) {
  int wave = (blockIdx.x << 2) + (threadIdx.x >> 6);
  int lane = threadIdx.x & 63;
  int b = wave >> 9;
  const int* st = story + wave * TT;
  size_t r0 = (size_t)st[0] * DD, r1 = (size_t)st[1] * DD;
  size_t r2 = (size_t)st[2] * DD, r3 = (size_t)st[3] * DD;
  const float4* t4 = (const float4*)table;
  const float4* ur = (const float4*)(u + (size_t)b * DD);
  float acc = 0.f;
#pragma unroll
  for (int h = 0; h < 2; ++h) {
    int c = (h << 6) + lane;
    float4 a = t4[(r0 >> 2) + c];
    float4 bb = t4[(r1 >> 2) + c];
    float4 cc = t4[(r2 >> 2) + c];
    float4 d = t4[(r3 >> 2) + c];
    float4 q = ur[c];
    acc += (a.x + bb.x + cc.x + d.x) * q.x;
    acc += (a.y + bb.y + cc.y + d.y) * q.y;
    acc += (a.z + bb.z + cc.z + d.z) * q.z;
    acc += (a.w + bb.w + cc.w + d.w) * q.w;
  }
#pragma unroll
  for (int off = 32; off > 0; off >>= 1) acc += __shfl_xor(acc, off);
  if (lane == 0) s[wave] = acc;
}

// ---- out[b][j] = bias[j] + W[j]. (vin ? vin[b] : table[q[b]]). One wave per (b,j).
__global__ __launch_bounds__(256) void matvec_kernel(const float* __restrict__ W,
                                                     const float* __restrict__ bias,
                                                     const float* __restrict__ vin,
                                                     const int* __restrict__ q,
                                                     const float* __restrict__ table,
                                                     float* __restrict__ out) {
  int idx = (blockIdx.x << 2) + (threadIdx.x >> 6);  // b*1536 + j
  int lane = threadIdx.x & 63;
  int b = idx / 1536;
  int j = idx - b * 1536;
  const float* xb = vin ? (vin + (size_t)b * DD) : (table + (size_t)q[b] * DD);
  const float4* Wr = (const float4*)(W + (size_t)j * DD);
  const float4* xr = (const float4*)xb;
  float acc = 0.f;
#pragma unroll
  for (int h = 0; h < 2; ++h) {
    int c = (h << 6) + lane;
    float4 a = Wr[c];
    float4 qv = xr[c];
    acc += a.x * qv.x + a.y * qv.y + a.z * qv.z + a.w * qv.w;
  }
#pragma unroll
  for (int off = 32; off > 0; off >>= 1) acc += __shfl_xor(acc, off);
  if (lane == 0) out[idx] = acc + bias[j];
}

// ---- GRU gates: hidden = (1-z)*n + z*u
__global__ void gate_kernel(const float* __restrict__ gi, const float* __restrict__ gh,
                            const float* __restrict__ u, float* __restrict__ hidden,
                            float* __restrict__ out_h) {
  int i = blockIdx.x * 256 + threadIdx.x;  // B*D
  int b = i >> 9, d = i & 511;
  const float* gib = gi + b * 1536;
  const float* ghb = gh + b * 1536;
  float i_r = gib[d], i_z = gib[d + 512], i_n = gib[d + 1024];
  float h_r = ghb[d], h_z = ghb[d + 512], h_n = ghb[d + 1024];
  float r = 1.f / (1.f + expf(-(i_r + h_r)));
  float z = 1.f / (1.f + expf(-(i_z + h_z)));
  float n = tanhf(i_n + r * h_n);
  float h = (1.f - z) * n + z * u[i];
  hidden[i] = h;
  out_h[i] = h;
}

// ---- p_vocab[b][v] = Hcat[b][:] . W1[v][:] + W1b[v].  [32 x 32000], K = 1024.
// 256 threads, block tile 32b x 64v, thread tile 4b x 2v, K-chunk 32,
// register double-buffer staging. Grid = 500 (2 blocks/CU).
__global__ __launch_bounds__(256) void pvocab_kernel(const float* __restrict__ Hcat,
                                                     const float* __restrict__ W1,
                                                     const float* __restrict__ W1b,
                                                     float* __restrict__ out) {
  __shared__ float As[32][36];   // [k][b] + pad
  __shared__ float Bs[32][68];   // [k][v] + pad
  int t = threadIdx.x;
  int v0 = blockIdx.x * 64;
  int tb = t >> 5;          // 0..7 : b-group of 4
  int tv = t & 31;          // 0..31: v-pair
  int br = t >> 2;
  int bk = (t & 3) << 3;
  const float* Wp = W1 + (size_t)(v0 + br) * 1024 + bk;
  int ab = t >> 3;
  int ak = (t & 7) << 2;
  const float* Ap = Hcat + (size_t)ab * 1024 + ak;

  float acc[4][2] = {{0.f, 0.f}, {0.f, 0.f}, {0.f, 0.f}, {0.f, 0.f}};

  float4 aReg = *(const float4*)(Ap);
  float4 wReg0 = *(const float4*)(Wp);
  float4 wReg1 = *(const float4*)(Wp + 4);

  for (int k0 = 0; k0 < 1024; k0 += 32) {
    As[ak + 0][ab] = aReg.x; As[ak + 1][ab] = aReg.y;
    As[ak + 2][ab] = aReg.z; As[ak + 3][ab] = aReg.w;
    Bs[bk + 0][br] = wReg0.x; Bs[bk + 1][br] = wReg0.y;
    Bs[bk + 2][br] = wReg0.z; Bs[bk + 3][br] = wReg0.w;
    Bs[bk + 4][br] = wReg1.x; Bs[bk + 5][br] = wReg1.y;
    Bs[bk + 6][br] = wReg1.z; Bs[bk + 7][br] = wReg1.w;
    __syncthreads();
    if (k0 + 32 < 1024) {   // issue next chunk early; hides under FMAs
      aReg = *(const float4*)(Ap + k0 + 32);
      wReg0 = *(const float4*)(Wp + k0 + 32);
      wReg1 = *(const float4*)(Wp + k0 + 36);
    }
#pragma unroll
    for (int k = 0; k < 32; ++k) {
      float2 bv = *(const float2*)&Bs[k][tv * 2];
      float4 av = *(const float4*)&As[k][tb * 4];
      acc[0][0] += av.x * bv.x; acc[0][1] += av.x * bv.y;
      acc[1][0] += av.y * bv.x; acc[1][1] += av.y * bv.y;
      acc[2][0] += av.z * bv.x; acc[2][1] += av.z * bv.y;
      acc[3][0] += av.w * bv.x; acc[3][1] += av.w * bv.y;
    }
    __syncthreads();
  }
  int v = v0 + tv * 2;
  float b0 = W1b[v], b1 = W1b[v + 1];
#pragma unroll
  for (int i = 0; i < 4; ++i) {
    float2 r;
    r.x = acc[i][0] + b0;
    r.y = acc[i][1] + b1;
    *(float2*)(out + (size_t)(tb * 4 + i) * VV + v) = r;
  }
}

extern "C" void kernel_launch(void* const* d_in, const int* in_sizes, int n_in,
                              void* d_out, int out_size, void* d_ws, size_t ws_size,
                              hipStream_t stream) {
  const int* story = (const int*)d_in[0];
  const int* q = (const int*)d_in[1];
  const float* C_enc = (const float*)d_in[2];
  const float* C_dec = (const float*)d_in[3];
  const float* W_ih = (const float*)d_in[4];
  const float* W_hh = (const float*)d_in[5];
  const float* b_ih = (const float*)d_in[6];
  const float* b_hh = (const float*)d_in[7];
  const float* W1 = (const float*)d_in[8];
  const float* W1b = (const float*)d_in[9];
  float* out = (float*)d_out;

  const size_t VD = (size_t)VV * DD;
  const float* C1 = C_enc + 1 * VD;   // encoder hop tables
  const float* C2 = C_enc + 2 * VD;
  const float* C3 = C_enc + 3 * VD;
  const float* D0 = C_dec + 0 * VD;   // decoder hop tables
  const float* D1 = C_dec + 1 * VD;
  const float* D2 = C_dec + 2 * VD;

  float* part = (float*)d_ws;              // [B*32*D]
  float* u = part + (size_t)BB * 32 * DD;  // [B*D]
  float* s = u + BB * DD;                  // [B*M]
  float* gi = s + BB * MM;                 // [B*3D]
  float* gh = gi + BB * 3 * DD;            // [B*3D]
  float* hid = gh + BB * 3 * DD;           // [B*D]
  float* uk = hid + BB * DD;               // [B*D]
  float* hc = uk + BB * DD;                // [B*2D]

  float* p_ptr_out = out;
  float* p_vocab_out = out + BB * MM;
  float* hid_out = out + BB * MM + (size_t)BB * VV;

  dim3 blk(256);
  const int pwGrid = BB * 32;         // 1024 blocks (64 rows each)
  const int pdGrid = BB * MM / 4;     // 4096 blocks x 4 waves
  const int mvGrid = BB * 3 * DD / 4; // 3072 blocks
  const int ewGrid = BB * DD / 256;   // 64

  // ---------------- encoder (u0 = 0 => hop0 softmax uniform; C_enc[0] unused)
  // Each table's two gather passes are adjacent -> second pass is L3-hot.
  poolwsum_kernel<<<pwGrid, blk, 0, stream>>>(C1, story, nullptr, part);
  wsumB_kernel<<<ewGrid, blk, 0, stream>>>(part, nullptr, u);      // u1 = mean pool
  pooldot_kernel<<<pdGrid, blk, 0, stream>>>(C1, story, u, s);     // s1 (C1 L3-hot)
  poolwsum_kernel<<<pwGrid, blk, 0, stream>>>(C2, story, s, part); // softmax folded
  wsumB_kernel<<<ewGrid, blk, 0, stream>>>(part, u, u);            // u2
  pooldot_kernel<<<pdGrid, blk, 0, stream>>>(C2, story, u, s);     // s2 (C2 L3-hot)
  poolwsum_kernel<<<pwGrid, blk, 0, stream>>>(C3, story, s, part);
  wsumB_kernel<<<ewGrid, blk, 0, stream>>>(part, u, u);            // u3 = enc_hidden

  // ---------------- GRU step (embed folded into matvec_gi)
  matvec_kernel<<<mvGrid, blk, 0, stream>>>(W_ih, b_ih, nullptr, q, C_dec, gi);
  matvec_kernel<<<mvGrid, blk, 0, stream>>>(W_hh, b_hh, u, nullptr, nullptr, gh);
  gate_kernel<<<ewGrid, blk, 0, stream>>>(gi, gh, u, hid, hid_out);

  // ---------------- pointer decoder (C_dec[3] pooled is dead code)
  pooldot_kernel<<<pdGrid, blk, 0, stream>>>(D0, story, hid, s);   // hop0 logits
  poolwsum_kernel<<<pwGrid, blk, 0, stream>>>(D1, story, s, part);
  wsumB2_kernel<<<ewGrid, blk, 0, stream>>>(part, hid, uk, hc);    // o0, uk1, hcat
  pooldot_kernel<<<pdGrid, blk, 0, stream>>>(D1, story, uk, s);    // hop1 logits (D1 hot)
  poolwsum_kernel<<<pwGrid, blk, 0, stream>>>(D2, story, s, part);
  wsumB_kernel<<<ewGrid, blk, 0, stream>>>(part, uk, uk);          // uk2
  pooldot_kernel<<<pdGrid, blk, 0, stream>>>(D2, story, uk, p_ptr_out); // p_ptr (D2 hot)

  // ---------------- vocab projection
  pvocab_kernel<<<VV / 64, blk, 0, stream>>>(hc, W1, W1b, p_vocab_out);
}